// Round 6
// baseline (1053.103 us; speedup 1.0000x reference)
//
#include <hip/hip_runtime.h>
#include <stdint.h>

#define N4K 4096
#define BIGF 1e30f
#define POIS 0xAAAAAAAAu

// ---- full-wave shift-by-1 toward higher lanes; lane0 receives `oldv`
__device__ __forceinline__ float dpp_shr1(float oldv, float src) {
  int r = __builtin_amdgcn_update_dpp(__float_as_int(oldv), __float_as_int(src),
                                      0x138 /*wave_shr:1*/, 0xF, 0xF, false);
  return __int_as_float(r);
}

__device__ __forceinline__ void st_bnd(unsigned* p, float v) {
  __hip_atomic_store(p, __float_as_uint(v), __ATOMIC_RELAXED,
                     __HIP_MEMORY_SCOPE_AGENT);
}
__device__ __forceinline__ unsigned ld_bnd(const unsigned* p) {
  return __hip_atomic_load((unsigned*)p, __ATOMIC_RELAXED,
                           __HIP_MEMORY_SCOPE_AGENT);
}

// =============== K0: poison the handoff buffer ===============
__global__ void k_poison(unsigned* __restrict__ bnd) {
  bnd[(size_t)blockIdx.x * 256 + threadIdx.x] = POIS;
}

// =============== K1: cost matrix ct[j][i] = ||x_i - y_j|| ===============
__global__ __launch_bounds__(256) void k_cost(const float* __restrict__ X,
                                              const float* __restrict__ Y,
                                              float* __restrict__ ct) {
  __shared__ __align__(16) float ys[64][132];
  __shared__ __align__(16) float xs[64][132];
  __shared__ float ynm[128];
  __shared__ float xnm[128];
  const int tid = threadIdx.x;
  const int jt = blockIdx.y << 7;
  const int it = blockIdx.x << 7;
#pragma unroll
  for (int r = 0; r < 32; ++r) {
    int e = tid + (r << 8);
    int row = e >> 6, k = e & 63;
    ys[k][row] = Y[(size_t)(jt + row) * 64 + k];
    xs[k][row] = X[(size_t)(it + row) * 64 + k];
  }
  __syncthreads();
  {
    int r = tid & 127;
    float s = 0.f;
    if (tid < 128) {
#pragma unroll
      for (int k = 0; k < 64; ++k) { float v = ys[k][r]; s = fmaf(v, v, s); }
      ynm[r] = s;
    } else {
#pragma unroll
      for (int k = 0; k < 64; ++k) { float v = xs[k][r]; s = fmaf(v, v, s); }
      xnm[r] = s;
    }
  }
  __syncthreads();
  const int tx = tid & 15, ty = tid >> 4;
  float acc[8][8];
#pragma unroll
  for (int r = 0; r < 8; ++r)
#pragma unroll
    for (int c = 0; c < 8; ++c) acc[r][c] = 0.f;
#pragma unroll 4
  for (int k = 0; k < 64; ++k) {
    float a[8], b[8];
    *(float4*)&a[0] = *(const float4*)&ys[k][(ty << 2)];
    *(float4*)&a[4] = *(const float4*)&ys[k][64 + (ty << 2)];
    *(float4*)&b[0] = *(const float4*)&xs[k][(tx << 2)];
    *(float4*)&b[4] = *(const float4*)&xs[k][64 + (tx << 2)];
#pragma unroll
    for (int r = 0; r < 8; ++r)
#pragma unroll
      for (int c = 0; c < 8; ++c) acc[r][c] = fmaf(a[r], b[c], acc[r][c]);
  }
#pragma unroll
  for (int r = 0; r < 8; ++r) {
    const int lr = ((r & 4) << 4) + (ty << 2) + (r & 3);
    const float yn = ynm[lr];
    float o[8];
#pragma unroll
    for (int c = 0; c < 8; ++c) {
      const int lc = ((c & 4) << 4) + (tx << 2) + (c & 3);
      float sq = yn + xnm[lc] - 2.f * acc[r][c];
      o[c] = sqrtf(fmaxf(sq, 1e-12f));
    }
    float* dst = ct + (size_t)(jt + lr) * N4K + it;
    *(float4*)(dst + (tx << 2)) = make_float4(o[0], o[1], o[2], o[3]);
    *(float4*)(dst + 64 + (tx << 2)) = make_float4(o[4], o[5], o[6], o[7]);
  }
}

// =============== K2: pipelined wavefront DP ===============
// 64 blocks x 1 wave; strip s = rows i in [64s,64s+64); lane l at step u
// computes cell (i=64s+l, j=u-l).  D = min3(up,left,diag+c)+c, eprev off-chain.
//
// Staging (the r5 fix): NO global_load_lds (its opaque LDS aliasing forces
// compiler s_waitcnt vmcnt(0) before every ds_read batch, draining the
// ~1000cy agent write-through stores in the same in-order vmcnt queue).
// Instead: 4 rotating reg-buffers of 16 rows (static indexing), loads issued
// 2 slots (~700cy) before their ds_write.  ds_reads depend only on lgkmcnt;
// the only vmcnt waits are COUNTED waits for 2-slot-old loads, and since
// loads are issued before each slot's stores, in-order retirement means
// those waits never block on stores.  Stores retire lazily, off-path.
// Slot schedule (slot m = 4n+k, rows R(a) = j in [16a,16a+16)):
//   slot m: ds_write R(m+2) (loaded at slot m-2) ; issue loads R(m+4)
//   buffer: load into buf[m%4], write from buf[(m-2)%4]  (period 4 = 1 iter)
// Ring tl: un-skewed (j,i), 256 rows + 16 mirror rows (256..271 copy 0..15,
// rewritten every time ring rows 0..15 are). Banks 2-way everywhere = free.
template <bool DO_NXTQ, bool PRED>
__device__ __forceinline__ void run_iter(const float* tl, const float* topb,
                                         int ubb, float (&curc)[16],
                                         float4 (&curq)[4], float (&nxtc)[16],
                                         float4 (&nxtq)[4], float& d,
                                         float& eprev, int lane, bool is00,
                                         bool doSt, unsigned* bdst) {
  const int nub = ubb + 16;
  const float* ba = tl + (((nub - lane) & 255) << 6) + lane;
#pragma unroll
  for (int s = 0; s < 16; ++s) nxtc[s] = ba[s << 6];
  if (DO_NXTQ) {
#pragma unroll
    for (int q = 0; q < 4; ++q)
      nxtq[q] = *(const float4*)&topb[(nub + (q << 2)) & 127];
  }
  float g0 = 0.f, g1 = 0.f, g2v = 0.f, g3 = 0.f;
#pragma unroll
  for (int s = 0; s < 16; ++s) {
    const int u = ubb + s;
    const float cst = curc[s];
    const float cnx = (s < 15) ? curc[s + 1] : nxtc[0];
    const float4 qq = curq[s >> 2];
    const float tqe = ((s & 3) == 0)   ? qq.x
                      : ((s & 3) == 1) ? qq.y
                      : ((s & 3) == 2) ? qq.z
                                       : qq.w;
    float n1 = dpp_shr1(tqe, d);  // up; lane0 <- top boundary
    float dn = fminf(fminf(n1, d), eprev) + cst;
    if (PRED) {
      if (is00 && u == 0) dn = cst;              // D[0][0] = c[0][0]
      if ((unsigned)(u - lane) > 4095u) dn = d;  // freeze invalid columns
    }
    eprev = n1 + cnx;  // next step's diag+c, off the dependency chain
    d = dn;
    if ((s & 3) == 0) g0 = d;
    if ((s & 3) == 1) g1 = d;
    if ((s & 3) == 2) g2v = d;
    if ((s & 3) == 3) {
      g3 = d;
      if (doSt) {  // lane 63 of a producing strip: publish bottom row
        const int jb = u - 66;
        if (PRED) {
          if ((unsigned)(jb + 0) <= 4095u) st_bnd(bdst + (jb + 0), g0);
          if ((unsigned)(jb + 1) <= 4095u) st_bnd(bdst + (jb + 1), g1);
          if ((unsigned)(jb + 2) <= 4095u) st_bnd(bdst + (jb + 2), g2v);
          if ((unsigned)(jb + 3) <= 4095u) st_bnd(bdst + (jb + 3), g3);
        } else {
          st_bnd(bdst + (jb + 0), g0);
          st_bnd(bdst + (jb + 1), g1);
          st_bnd(bdst + (jb + 2), g2v);
          st_bnd(bdst + (jb + 3), g3);
        }
      }
    }
  }
}

__global__ __launch_bounds__(64) void k_dp(const float* __restrict__ ct,
                                           unsigned* __restrict__ bnd,
                                           float* __restrict__ out) {
  __shared__ __align__(16) float tl[272 * 64];  // 68KB: 4-chunk ring + mirror
  __shared__ __align__(16) float topb[128];     // 2-chunk top-boundary ring
  const int lane = threadIdx.x;
  const int b = (int)blockIdx.x;
  const int strip = ((b & 7) << 3) | (b >> 3);  // consecutive strips same XCD
  const int i0 = strip << 6;
  const bool hasTop = (strip != 0);
  const bool doSt = (strip != 63) && (lane == 63);
  const bool is00 = (strip == 0) && (lane == 0);
  const unsigned* bsrc = bnd + (size_t)(hasTop ? strip - 1 : 0) * N4K;
  unsigned* bdst = bnd + (size_t)strip * N4K;

  float bufA[16], bufB[16], bufC[16], bufD[16];  // 4 rotating stage buffers

  auto loadB = [&](float (&buf)[16], int a) {  // rows R(a), clamped, coalesced
    const float* gb = ct + i0 + lane;
#pragma unroll
    for (int r = 0; r < 16; ++r) {
      int j = (a << 4) + r;
      j = j > N4K - 1 ? N4K - 1 : j;
      buf[r] = gb[(size_t)j * N4K];
    }
  };
  auto writeB = [&](float (&buf)[16], int a) {  // rows R(a) -> ring (+mirror)
    float* wb = tl + (((a << 4) & 255) << 6) + lane;
#pragma unroll
    for (int r = 0; r < 16; ++r) wb[r << 6] = buf[r];
    if (((a << 4) & 255) == 0) {
      float* wm = tl + (256 << 6) + lane;
#pragma unroll
      for (int r = 0; r < 16; ++r) wm[r << 6] = buf[r];
    }
  };

  // ---- prologue: R(0..3) loaded; R(0),R(1) in LDS; bufC=R(2), bufD=R(3)
  unsigned tvP = 0, tvN = 0;
  if (hasTop) tvP = ld_bnd(bsrc + lane);
  loadB(bufA, 0);
  loadB(bufB, 1);
  loadB(bufC, 2);
  loadB(bufD, 3);
  writeB(bufA, 0);
  writeB(bufB, 1);
  if (hasTop) {
    int gc = 0;
    while (__any((int)(tvP == POIS)) && ++gc < (1 << 16))
      tvP = ld_bnd(bsrc + lane);
    topb[lane] = __uint_as_float(tvP);
    // lead-margin: also wait for producer chunk 1 (establish ~196-step lead
    // >> ~132 required -> steady-state polls succeed first-try)
    unsigned t2 = ld_bnd(bsrc + 64 + lane);
    gc = 0;
    while (__any((int)(t2 == POIS)) && ++gc < (1 << 16))
      t2 = ld_bnd(bsrc + 64 + lane);
  } else {
    topb[lane] = BIGF;  // strip 0: top boundary +inf forever (both slots)
    topb[64 + lane] = BIGF;
  }

  float cA[16], cB[16];
  float4 qA[4], qB[4];
  {
    const float* ba0 = tl + (((0 - lane) & 255) << 6) + lane;
#pragma unroll
    for (int s = 0; s < 16; ++s) cA[s] = ba0[s << 6];
  }
#pragma unroll
  for (int q = 0; q < 4; ++q) qA[q] = *(const float4*)&topb[(q << 2)];

  float d = BIGF, eprev = BIGF;

  auto pollQ = [&](int q, int n) {  // finalize quarter q of chunk n's topb
    int gc = 0;
    while (__any((int)((lane >> 4) == q && tvP == POIS)) && ++gc < (1 << 16))
      tvP = ld_bnd(bsrc + (n << 6) + lane);
    if ((lane >> 4) == q) topb[((n & 1) << 6) + lane] = __uint_as_float(tvP);
  };

#pragma unroll 1
  for (int n = 0; n <= 64; ++n) {
    const int m0 = n << 2;
    const bool doTv = hasTop && (n + 1 <= 63);
    if (doTv) tvN = ld_bnd(bsrc + ((n + 1) << 6) + lane);  // early issue
    const bool doQ = hasTop && (n <= 63);
    const int ub = n << 6;
    // ---- slot k=0: loads first (stores stay younger), then ds_write
    loadB(bufA, m0 + 4);
    writeB(bufC, m0 + 2);
    if (doQ) pollQ(1, n);
    if (n == 0 || n == 64) {
      run_iter<true, true>(tl, topb, ub + 0, cA, qA, cB, qB, d, eprev, lane,
                           is00, doSt, bdst);
      loadB(bufB, m0 + 5);
      writeB(bufD, m0 + 3);
      if (doQ) pollQ(2, n);
      run_iter<true, true>(tl, topb, ub + 16, cB, qB, cA, qA, d, eprev, lane,
                           is00, doSt, bdst);
      loadB(bufC, m0 + 6);
      writeB(bufA, m0 + 4);
      if (doQ) pollQ(3, n);
      run_iter<true, true>(tl, topb, ub + 32, cA, qA, cB, qB, d, eprev, lane,
                           is00, doSt, bdst);
      loadB(bufD, m0 + 7);
      writeB(bufB, m0 + 5);
      run_iter<false, true>(tl, topb, ub + 48, cB, qB, cA, qA, d, eprev, lane,
                            is00, doSt, bdst);
    } else {
      run_iter<true, false>(tl, topb, ub + 0, cA, qA, cB, qB, d, eprev, lane,
                            is00, doSt, bdst);
      loadB(bufB, m0 + 5);
      writeB(bufD, m0 + 3);
      if (doQ) pollQ(2, n);
      run_iter<true, false>(tl, topb, ub + 16, cB, qB, cA, qA, d, eprev, lane,
                            is00, doSt, bdst);
      loadB(bufC, m0 + 6);
      writeB(bufA, m0 + 4);
      if (doQ) pollQ(3, n);
      run_iter<true, false>(tl, topb, ub + 32, cA, qA, cB, qB, d, eprev, lane,
                            is00, doSt, bdst);
      loadB(bufD, m0 + 7);
      writeB(bufB, m0 + 5);
      run_iter<false, false>(tl, topb, ub + 48, cB, qB, cA, qA, d, eprev, lane,
                             is00, doSt, bdst);
    }
    if (doTv) {  // quarter 0 of chunk n+1, then carry tvN -> tvP
      int gc = 0;
      while (__any((int)((lane >> 4) == 0 && tvN == POIS)) && ++gc < (1 << 16))
        tvN = ld_bnd(bsrc + ((n + 1) << 6) + lane);
      if ((lane >> 4) == 0)
        topb[(((n + 1) & 1) << 6) + lane] = __uint_as_float(tvN);
      tvP = tvN;
    }
#pragma unroll
    for (int q = 0; q < 4; ++q)  // pre-read next chunk's first top quads
      qA[q] = *(const float4*)&topb[((ub + 64) + (q << 2)) & 127];
  }
  if (strip == 63 && lane == 63) out[0] = d;  // D[4095][4095]
}

extern "C" void kernel_launch(void* const* d_in, const int* in_sizes, int n_in,
                              void* d_out, int out_size, void* d_ws,
                              size_t ws_size, hipStream_t stream) {
  (void)in_sizes; (void)n_in; (void)out_size; (void)ws_size;
  const float* X = (const float*)d_in[0];
  const float* Y = (const float*)d_in[1];
  float* out = (float*)d_out;
  float* ct = (float*)d_ws;  // 64 MB
  unsigned* bnd = (unsigned*)((char*)d_ws + (size_t)N4K * N4K * sizeof(float));

  k_poison<<<1024, 256, 0, stream>>>(bnd);  // 1 MB handoff buffer
  k_cost<<<dim3(32, 32), 256, 0, stream>>>(X, Y, ct);
  k_dp<<<64, 64, 0, stream>>>(ct, bnd, out);
}